// Round 3
// baseline (4616.329 us; speedup 1.0000x reference)
//
#include <hip/hip_runtime.h>

typedef _Float16 f16;
typedef _Float16 f16x8 __attribute__((ext_vector_type(8)));
typedef _Float16 f16x4 __attribute__((ext_vector_type(4)));
typedef float f32x4 __attribute__((ext_vector_type(4)));

#define B_ 128
#define T_ 512
#define H_ 192
#define G3 576
#define NX 1152

// ---- workspace layout (bytes). Total 204,718,080 < 256 MiB. ----
// [0, 150994944)          gxb : gx pre-acts, f16 [d][bblk][t][w][lq][l16][s][q][i]
//                               (per (d,bblk): 512*9216 elems; per t: 9216 elems)
// [150994944, 201326592)  hbuf: layer h output, f16 [t][b][384]
//                               (in0 f16 [t][b][128] aliases its first 16.8MB)
// [201326592, 203390976)  wihf: f16 w_ih (L0 147456, L1 442368, L2 442368)
// [203390976, 204718080)  whhf: f16 w_hh (3 x 221184)
#define OFF_H   150994944u
#define OFF_WIH 201326592u
#define OFF_WHH 203390976u

__device__ __forceinline__ void gload_lds16(const void* g, void* l) {
  __builtin_amdgcn_global_load_lds(
      (const __attribute__((address_space(1))) unsigned int*)g,
      (__attribute__((address_space(3))) unsigned int*)l, 16, 0, 0);
}

__device__ __forceinline__ float sigm(float x) {
  return __fdividef(1.f, 1.f + __expf(-x));
}
__device__ __forceinline__ float tanhf_(float x) {
  float ax = fabsf(x);
  float e = __expf(-2.f * ax);
  float t = __fdividef(1.f - e, 1.f + e);
  return copysignf(t, x);
}

// ---------------- weight f32 -> f16 conversion ----------------
__global__ void wconv_kernel(const float* __restrict__ s0, const float* __restrict__ h0,
                             const float* __restrict__ s1, const float* __restrict__ h1,
                             const float* __restrict__ s2, const float* __restrict__ h2,
                             f16* __restrict__ wih, f16* __restrict__ whh) {
  const int stride = gridDim.x * blockDim.x;
  for (int i = blockIdx.x * blockDim.x + threadIdx.x; i < 1695744; i += stride) {
    if (i < 1032192) {
      f16 v;
      if (i < 147456) v = (f16)s0[i];
      else if (i < 589824) v = (f16)s1[i - 147456];
      else v = (f16)s2[i - 589824];
      wih[i] = v;
    } else {
      int j = i - 1032192;
      f16 v;
      if (j < 221184) v = (f16)h0[j];
      else if (j < 442368) v = (f16)h1[j - 221184];
      else v = (f16)h2[j - 442368];
      whh[j] = v;
    }
  }
}

// ---------------- embedding gather -> f16, out layout [t][b][128] ----------------
__global__ void embed_kernel(const int* __restrict__ x, const float* __restrict__ emb,
                             f16* __restrict__ o) {
  const int row = (blockIdx.x << 2) + (threadIdx.x >> 6);  // b*512+t
  const int lane = threadIdx.x & 63;
  const int b = row >> 9, t = row & 511;
  const int idx = x[row];
  const float2 v = *(const float2*)(emb + ((size_t)idx << 7) + (lane << 1));
  union { f16 h[2]; unsigned u; } p;
  p.h[0] = (f16)v.x;
  p.h[1] = (f16)v.y;
  *(unsigned*)(o + ((size_t)((t << 7) + b) << 7) + (lane << 1)) = p.u;
}

// ---------------- gx GEMM: gx = X @ w_ih^T + b_ih (f16 MFMA) ----------------
// A: [t][b][DIN] f16.  W: [1152][DIN] f16.  Output: scan-ready layout (see ws map).
template <int DIN>
__global__ __launch_bounds__(256) void gx_gemm(const f16* __restrict__ A,
                                               const f16* __restrict__ W,
                                               const float* __restrict__ bih,
                                               f16* __restrict__ gxo) {
  const int t = blockIdx.x;        // M-tile: all 128 b at this t
  const int nt0 = blockIdx.y << 7; // N-tile base (128 wide)
  const int tid = threadIdx.x;
  const int lane = tid & 63;
  const int w = tid >> 6;
  const int l16 = lane & 15;
  const int lq = lane >> 4;
  const int wm = (w >> 1) << 6;
  const int wn = (w & 1) << 6;

  __shared__ __align__(16) f16 Al[128 * 128];
  __shared__ __align__(16) f16 Bl[128 * 128];

  f32x4 acc[4][4] = {};

  const int srow = tid >> 4;  // staging row-within-16
  const int sc = tid & 15;    // staging phys chunk

  for (int kk = 0; kk < DIN; kk += 128) {
    __syncthreads();
#pragma unroll
    for (int it = 0; it < 8; ++it) {
      const int r = (it << 4) + srow;
      const int cl = sc ^ (r & 7);
      gload_lds16(A + (size_t)(t * B_ + r) * DIN + kk + cl * 8, Al + (it << 11) + tid * 8);
      const int n = nt0 + r;
      gload_lds16(W + (size_t)n * DIN + kk + cl * 8, Bl + (it << 11) + tid * 8);
    }
    __syncthreads();
#pragma unroll
    for (int kt = 0; kt < 4; ++kt) {
      f16x8 af[4], bf[4];
#pragma unroll
      for (int mt = 0; mt < 4; ++mt) {
        const int r = wm + (mt << 4) + l16;
        const int c = ((kt << 2) + lq) ^ (r & 7);
        af[mt] = *(const f16x8*)(Al + (r << 7) + (c << 3));
      }
#pragma unroll
      for (int nt = 0; nt < 4; ++nt) {
        const int r = wn + (nt << 4) + l16;
        const int c = ((kt << 2) + lq) ^ (r & 7);
        bf[nt] = *(const f16x8*)(Bl + (r << 7) + (c << 3));
      }
#pragma unroll
      for (int mt = 0; mt < 4; ++mt)
#pragma unroll
        for (int nt = 0; nt < 4; ++nt)
          acc[mt][nt] = __builtin_amdgcn_mfma_f32_16x16x32_f16(af[mt], bf[nt], acc[mt][nt], 0, 0, 0);
    }
  }
  // epilogue: + b_ih, pack i=0..3 (batch%4) into one 8B store to scan layout.
  // C frag layout: row(batch) = lq*4+i, col(gate) = l16.
#pragma unroll
  for (int nt = 0; nt < 4; ++nt) {
    const int ncol = nt0 + wn + (nt << 4);      // tile base gate index (16-aligned)
    const float bias = bih[ncol + l16];
    const int ntile = ncol >> 4;                 // 0..71
    const int d = (ntile >= 36) ? 1 : 0;
    const int g16 = ntile - 36 * d;
    const int s = g16 / 12;
    const int c16 = g16 % 12;
    const int ws_ = c16 / 3;
    const int q = c16 % 3;
#pragma unroll
    for (int mt = 0; mt < 4; ++mt) {
      const int bblk = (wm >> 4) + mt;
      f16x4 pk;
#pragma unroll
      for (int i = 0; i < 4; ++i) pk[i] = (f16)(acc[mt][nt][i] + bias);
      const size_t off =
          ((((((size_t)(d * 8 + bblk) * 512 + t) * 4 + ws_) * 4 + lq) * 16 + l16) * 9 +
           (s * 3 + q)) * 4;
      *(f16x4*)(gxo + off) = pk;
    }
  }
}

// ---------------- recurrent scan (latency-optimized) ----------------
// 16 blocks: (8 batch-blocks of 16 rows) x (2 dirs). 4 waves; wave w owns h-cols
// [48w,48w+48) and gate tiles {s*192+w*48+q*16}. w_hh resident in regs. h state f32.
// gx prefetched one step ahead into regs (contiguous 72B/lane); raw barrier with
// lgkmcnt-only drain keeps prefetch + out-stores in flight across steps.
__global__ __launch_bounds__(256, 1) void gru_scan(const f16* __restrict__ gx,
                                                   const f16* __restrict__ whh,
                                                   const float* __restrict__ bhh,
                                                   f16* __restrict__ out,
                                                   int last) {
  const int bx = blockIdx.x;
  const int d = bx & 1;
  const int bblk = bx >> 1;
  const int b0 = bblk << 4;
  const int tid = threadIdx.x;
  const int lane = tid & 63;
  const int w = tid >> 6;
  const int l16 = lane & 15;
  const int lq = lane >> 4;

  // h tile as next-step A-fragments; 400B row stride (b128 wave read = 8-phase floor)
  __shared__ __align__(16) f16 hl[2][16][200];
  for (int i = tid; i < 2 * 16 * 200; i += 256) ((f16*)hl)[i] = (f16)0.f;

  const f16* whd = whh + (size_t)d * (G3 * H_);
  f16x8 wf[3][3][6];
#pragma unroll
  for (int s = 0; s < 3; ++s)
#pragma unroll
    for (int q = 0; q < 3; ++q) {
      const int nrow = s * 192 + w * 48 + q * 16 + l16;
#pragma unroll
      for (int kt = 0; kt < 6; ++kt)
        wf[s][q][kt] = *(const f16x8*)(whd + (size_t)nrow * H_ + kt * 32 + lq * 8);
    }
  float bh[3][3];
#pragma unroll
  for (int s = 0; s < 3; ++s)
#pragma unroll
    for (int q = 0; q < 3; ++q)
      bh[s][q] = bhh[d * G3 + s * 192 + w * 48 + q * 16 + l16];

  float hreg[3][4];
#pragma unroll
  for (int q = 0; q < 3; ++q)
#pragma unroll
    for (int i = 0; i < 4; ++i) hreg[q][i] = 0.f;

  const int nsteps = (last && d == 1) ? 1 : T_;
  const bool fwd = (d == 0);
  // per-lane gx base: [d][bblk] block + [w][lq][l16] lane slot; step adds t*9216
  const f16* gbase = gx + (size_t)(d * 8 + bblk) * 4718592 +
                     (size_t)(((w * 4 + lq) * 16 + l16) * 36);

  f16x4 pf[9], pfN[9];
  {
    const int t0 = fwd ? 0 : (T_ - 1);
    const f16x4* p = (const f16x4*)(gbase + (size_t)t0 * 9216);
#pragma unroll
    for (int j = 0; j < 9; ++j) pf[j] = p[j];
  }
  __syncthreads();

  // one GRU step: consumes pc (this step's gx), prefetches into pn (next step's gx)
  auto body = [&](int step, int buf, f16x4 (&pc)[9], f16x4 (&pn)[9]) {
    const int t = fwd ? step : (T_ - 1 - step);
    f32x4 acc[3][3];
#pragma unroll
    for (int s = 0; s < 3; ++s)
#pragma unroll
      for (int q = 0; q < 3; ++q) {
        const float bv = bh[s][q];
        acc[s][q] = (f32x4){bv, bv, bv, bv};
      }
#pragma unroll
    for (int kt = 0; kt < 6; ++kt) {
      const f16x8 af = *(const f16x8*)(&hl[buf][l16][kt * 32 + lq * 8]);
#pragma unroll
      for (int s = 0; s < 3; ++s)
#pragma unroll
        for (int q = 0; q < 3; ++q)
          acc[s][q] = __builtin_amdgcn_mfma_f32_16x16x32_f16(af, wf[s][q][kt], acc[s][q], 0, 0, 0);
    }
    // prefetch next step's gx (independent; overlaps gate VALU + barrier + next MFMAs)
    if (step + 1 < nsteps) {
      const int tn = fwd ? (step + 1) : (T_ - 2 - step);
      const f16x4* p = (const f16x4*)(gbase + (size_t)tn * 9216);
#pragma unroll
      for (int j = 0; j < 9; ++j) pn[j] = p[j];
    }
    const bool wr = (!last) || (t == T_ - 1);
#pragma unroll
    for (int q = 0; q < 3; ++q)
#pragma unroll
      for (int i = 0; i < 4; ++i) {
        const float r = sigm((float)pc[q][i] + acc[0][q][i]);
        const float z = sigm((float)pc[3 + q][i] + acc[1][q][i]);
        const float n = tanhf_((float)pc[6 + q][i] + r * acc[2][q][i]);
        const float h = n + z * (hreg[q][i] - n);
        hreg[q][i] = h;
        hl[buf ^ 1][(lq << 2) + i][w * 48 + q * 16 + l16] = (f16)h;
        if (wr)
          out[((size_t)t * B_ + b0 + (lq << 2) + i) * 384 + d * H_ + w * 48 + q * 16 + l16] = (f16)h;
      }
    // drain LDS only; prefetch loads + global stores stay in flight across barrier
    asm volatile("s_waitcnt lgkmcnt(0)" ::: "memory");
    __builtin_amdgcn_sched_barrier(0);
    __builtin_amdgcn_s_barrier();
    __builtin_amdgcn_sched_barrier(0);
  };

  if (nsteps == 1) {
    body(0, 0, pf, pfN);
  } else {
    for (int step = 0; step < T_; step += 2) {
      body(step, 0, pf, pfN);
      body(step + 1, 1, pfN, pf);
    }
  }
}

// ---------------- FC head ----------------
__global__ void fc_kernel(const f16* __restrict__ h2, const float* __restrict__ w1,
                          const float* __restrict__ b1, const float* __restrict__ w2,
                          const float* __restrict__ b2, float* __restrict__ y) {
  const int b = blockIdx.x;
  const int i = threadIdx.x;  // 128 threads = fc1 units
  __shared__ float hs[384];
  __shared__ float us[128];
  const f16* hp = h2 + ((size_t)(T_ - 1) * B_ + b) * 384;
  for (int k = i; k < 384; k += 128) hs[k] = (float)hp[k];
  __syncthreads();
  float a = b1[i];
  for (int k = 0; k < 384; ++k) a = fmaf(w1[i * 384 + k], hs[k], a);
  us[i] = fmaxf(a, 0.f) * w2[i];
  __syncthreads();
  if (i == 0) {
    float s = b2[0];
    for (int k = 0; k < 128; ++k) s += us[k];
    y[b] = s;
  }
}

extern "C" void kernel_launch(void* const* d_in, const int* in_sizes, int n_in,
                              void* d_out, int out_size, void* d_ws, size_t ws_size,
                              hipStream_t stream) {
  const int* x = (const int*)d_in[0];
  const float* emb = (const float*)d_in[1];
  const float* wih[3] = {(const float*)d_in[2], (const float*)d_in[6], (const float*)d_in[10]};
  const float* whh[3] = {(const float*)d_in[3], (const float*)d_in[7], (const float*)d_in[11]};
  const float* bih[3] = {(const float*)d_in[4], (const float*)d_in[8], (const float*)d_in[12]};
  const float* bhh[3] = {(const float*)d_in[5], (const float*)d_in[9], (const float*)d_in[13]};
  const float* fc1w = (const float*)d_in[14];
  const float* fc1b = (const float*)d_in[15];
  const float* fc2w = (const float*)d_in[16];
  const float* fc2b = (const float*)d_in[17];
  float* y = (float*)d_out;

  char* ws = (char*)d_ws;
  f16* gxb = (f16*)(ws);             // 150,994,944 B
  f16* hbuf = (f16*)(ws + OFF_H);    // 50,331,648 B (single h buffer for all layers)
  f16* in0 = hbuf;                   // embedding output aliases hbuf start (dead after gemm0)
  f16* wihf = (f16*)(ws + OFF_WIH);
  f16* whhf = (f16*)(ws + OFF_WHH);

  wconv_kernel<<<1024, 256, 0, stream>>>(wih[0], whh[0], wih[1], whh[1], wih[2], whh[2], wihf, whhf);
  embed_kernel<<<16384, 256, 0, stream>>>(x, emb, in0);

  // layer 0
  gx_gemm<128><<<dim3(512, 9), 256, 0, stream>>>(in0, wihf, bih[0], gxb);
  gru_scan<<<16, 256, 0, stream>>>(gxb, whhf, bhh[0], hbuf, 0);
  // layer 1
  gx_gemm<384><<<dim3(512, 9), 256, 0, stream>>>(hbuf, wihf + 147456, bih[1], gxb);
  gru_scan<<<16, 256, 0, stream>>>(gxb, whhf + 221184, bhh[1], hbuf, 0);
  // layer 2 (bwd dir needs only 1 step; fwd writes only t=511)
  gx_gemm<384><<<dim3(512, 9), 256, 0, stream>>>(hbuf, wihf + 147456 + 442368, bih[2], gxb);
  gru_scan<<<16, 256, 0, stream>>>(gxb, whhf + 2 * 221184, bhh[2], hbuf, 1);

  fc_kernel<<<128, 128, 0, stream>>>(hbuf, fc1w, fc1b, fc2w, fc2b, y);
}

// Round 4
// 2086.661 us; speedup vs baseline: 2.2123x; 2.2123x over previous
//
#include <hip/hip_runtime.h>

typedef _Float16 f16;
typedef _Float16 f16x8 __attribute__((ext_vector_type(8)));
typedef _Float16 f16x4 __attribute__((ext_vector_type(4)));
typedef float f32x4 __attribute__((ext_vector_type(4)));

#define B_ 128
#define T_ 512
#define H_ 192
#define G3 576
#define NX 1152

// ---- workspace layout (bytes). Total 204,718,080 < 256 MiB. ----
// [0, 150994944)          gxb : gx pre-acts, f16 [d][bblk][t][w12][lq][l16][s*4+i]
//                               (per (d,bblk): 512*9216 elems; per t: 9216 elems)
// [150994944, 201326592)  hbuf: layer h output, f16 [t][b][384]
//                               (in0 f16 [t][b][128] aliases its first 16.8MB)
// [201326592, 203390976)  wihf: f16 w_ih (L0 147456, L1 442368, L2 442368)
// [203390976, 204718080)  whhf: f16 w_hh (3 x 221184)
#define OFF_H   150994944u
#define OFF_WIH 201326592u
#define OFF_WHH 203390976u

__device__ __forceinline__ void gload_lds16(const void* g, void* l) {
  __builtin_amdgcn_global_load_lds(
      (const __attribute__((address_space(1))) unsigned int*)g,
      (__attribute__((address_space(3))) unsigned int*)l, 16, 0, 0);
}

// sigmoid/tanh with exactly 2 hardware trans ops each (v_exp_f32 + v_rcp_f32)
#define LOG2E 1.44269504088896f
__device__ __forceinline__ float sigm_fast(float x) {
  return __builtin_amdgcn_rcpf(1.f + __builtin_amdgcn_exp2f(x * -LOG2E));
}
__device__ __forceinline__ float tanh_fast(float x) {
  // tanh(x) = 1 - 2/(exp2(2*log2e*x) + 1); correct limits at +/-inf, NaN-free
  return fmaf(-2.f, __builtin_amdgcn_rcpf(1.f + __builtin_amdgcn_exp2f(x * (2.f * LOG2E))), 1.f);
}

// ---------------- weight f32 -> f16 conversion ----------------
__global__ void wconv_kernel(const float* __restrict__ s0, const float* __restrict__ h0,
                             const float* __restrict__ s1, const float* __restrict__ h1,
                             const float* __restrict__ s2, const float* __restrict__ h2,
                             f16* __restrict__ wih, f16* __restrict__ whh) {
  const int stride = gridDim.x * blockDim.x;
  for (int i = blockIdx.x * blockDim.x + threadIdx.x; i < 1695744; i += stride) {
    if (i < 1032192) {
      f16 v;
      if (i < 147456) v = (f16)s0[i];
      else if (i < 589824) v = (f16)s1[i - 147456];
      else v = (f16)s2[i - 589824];
      wih[i] = v;
    } else {
      int j = i - 1032192;
      f16 v;
      if (j < 221184) v = (f16)h0[j];
      else if (j < 442368) v = (f16)h1[j - 221184];
      else v = (f16)h2[j - 442368];
      whh[j] = v;
    }
  }
}

// ---------------- embedding gather -> f16, out layout [t][b][128] ----------------
__global__ void embed_kernel(const int* __restrict__ x, const float* __restrict__ emb,
                             f16* __restrict__ o) {
  const int row = (blockIdx.x << 2) + (threadIdx.x >> 6);  // b*512+t
  const int lane = threadIdx.x & 63;
  const int b = row >> 9, t = row & 511;
  const int idx = x[row];
  const float2 v = *(const float2*)(emb + ((size_t)idx << 7) + (lane << 1));
  union { f16 h[2]; unsigned u; } p;
  p.h[0] = (f16)v.x;
  p.h[1] = (f16)v.y;
  *(unsigned*)(o + ((size_t)((t << 7) + b) << 7) + (lane << 1)) = p.u;
}

// ---------------- gx GEMM: gx = X @ w_ih^T + b_ih (f16 MFMA) ----------------
// A: [t][b][DIN] f16.  W: [1152][DIN] f16.  Output: scan-ready layout (see ws map).
template <int DIN>
__global__ __launch_bounds__(256) void gx_gemm(const f16* __restrict__ A,
                                               const f16* __restrict__ W,
                                               const float* __restrict__ bih,
                                               f16* __restrict__ gxo) {
  const int t = blockIdx.x;        // M-tile: all 128 b at this t
  const int nt0 = blockIdx.y << 7; // N-tile base (128 wide)
  const int tid = threadIdx.x;
  const int lane = tid & 63;
  const int w = tid >> 6;
  const int l16 = lane & 15;
  const int lq = lane >> 4;
  const int wm = (w >> 1) << 6;
  const int wn = (w & 1) << 6;

  __shared__ __align__(16) f16 Al[128 * 128];
  __shared__ __align__(16) f16 Bl[128 * 128];

  f32x4 acc[4][4] = {};

  const int srow = tid >> 4;  // staging row-within-16
  const int sc = tid & 15;    // staging phys chunk

  for (int kk = 0; kk < DIN; kk += 128) {
    __syncthreads();
#pragma unroll
    for (int it = 0; it < 8; ++it) {
      const int r = (it << 4) + srow;
      const int cl = sc ^ (r & 7);
      gload_lds16(A + (size_t)(t * B_ + r) * DIN + kk + cl * 8, Al + (it << 11) + tid * 8);
      const int n = nt0 + r;
      gload_lds16(W + (size_t)n * DIN + kk + cl * 8, Bl + (it << 11) + tid * 8);
    }
    __syncthreads();
#pragma unroll
    for (int kt = 0; kt < 4; ++kt) {
      f16x8 af[4], bf[4];
#pragma unroll
      for (int mt = 0; mt < 4; ++mt) {
        const int r = wm + (mt << 4) + l16;
        const int c = ((kt << 2) + lq) ^ (r & 7);
        af[mt] = *(const f16x8*)(Al + (r << 7) + (c << 3));
      }
#pragma unroll
      for (int nt = 0; nt < 4; ++nt) {
        const int r = wn + (nt << 4) + l16;
        const int c = ((kt << 2) + lq) ^ (r & 7);
        bf[nt] = *(const f16x8*)(Bl + (r << 7) + (c << 3));
      }
#pragma unroll
      for (int mt = 0; mt < 4; ++mt)
#pragma unroll
        for (int nt = 0; nt < 4; ++nt)
          acc[mt][nt] = __builtin_amdgcn_mfma_f32_16x16x32_f16(af[mt], bf[nt], acc[mt][nt], 0, 0, 0);
    }
  }
  // epilogue: + b_ih, pack i=0..3 (batch%4) into one 8B store to scan layout.
  // C frag layout: row(batch) = lq*4+i, col(gate) = l16.
#pragma unroll
  for (int nt = 0; nt < 4; ++nt) {
    const int ncol = nt0 + wn + (nt << 4);      // tile base gate index (16-aligned)
    const float bias = bih[ncol + l16];
    const int ntile = ncol >> 4;                 // 0..71
    const int d = (ntile >= 36) ? 1 : 0;
    const int g = ntile - 36 * d;
    const int s = g / 12;       // gate type r/z/n
    const int c12 = g % 12;     // col-tile = scan wave id
#pragma unroll
    for (int mt = 0; mt < 4; ++mt) {
      const int bblk = (wm >> 4) + mt;
      f16x4 pk;
#pragma unroll
      for (int i = 0; i < 4; ++i) pk[i] = (f16)(acc[mt][nt][i] + bias);
      const size_t off =
          (size_t)(((((d * 8 + bblk) * 512 + t) * 12 + c12) * 4 + lq) * 16 + l16) * 12 + s * 4;
      *(f16x4*)(gxo + off) = pk;
    }
  }
}

// ---------------- recurrent scan (VALU-throughput + TLP optimized) ----------------
// 16 blocks: (8 batch-blocks of 16 rows) x (2 dirs). 768 threads = 12 waves (3/SIMD
// for TLP). Wave w owns gate col-tile [16w,16w+16) for ALL 3 gate types; 18 MFMA and
// 4 gate elements per wave per step. w_hh resident in regs (72 VGPR). Native
// exp2/rcp gates. gx prefetched 2 steps ahead. Raw barrier keeps loads/stores in
// flight across steps.
__global__ __launch_bounds__(768, 3) void gru_scan(const f16* __restrict__ gx,
                                                   const f16* __restrict__ whh,
                                                   const float* __restrict__ bhh,
                                                   f16* __restrict__ out,
                                                   int last) {
  const int bx = blockIdx.x;
  const int d = bx & 1;
  const int bblk = bx >> 1;
  const int b0 = bblk << 4;
  const int tid = threadIdx.x;
  const int lane = tid & 63;
  const int w = tid >> 6;    // 0..11
  const int l16 = lane & 15;
  const int lq = lane >> 4;

  // h tile as next-step A-fragments; 400B row stride
  __shared__ __align__(16) f16 hl[2][16][200];
  for (int i = tid; i < 2 * 16 * 200; i += 768) ((f16*)hl)[i] = (f16)0.f;

  const f16* whd = whh + (size_t)d * (G3 * H_);
  // wave w's B-fragments: gate rows s*192 + w*16 + l16, all K
  f16x8 wf[3][6];
#pragma unroll
  for (int s = 0; s < 3; ++s) {
    const int nrow = s * 192 + w * 16 + l16;
#pragma unroll
    for (int kt = 0; kt < 6; ++kt)
      wf[s][kt] = *(const f16x8*)(whd + (size_t)nrow * H_ + kt * 32 + lq * 8);
  }
  float bh[3];
#pragma unroll
  for (int s = 0; s < 3; ++s) bh[s] = bhh[d * G3 + s * 192 + w * 16 + l16];

  float hreg[4];
#pragma unroll
  for (int i = 0; i < 4; ++i) hreg[i] = 0.f;

  const int nsteps = (last && d == 1) ? 1 : T_;
  const bool fwd = (d == 0);
  // per-lane gx slot: 12 f16 = [s*4+i], 24B contiguous
  const f16* gbase = gx + (size_t)(d * 8 + bblk) * 4718592 +
                     (size_t)(((w * 4 + lq) * 16 + l16) * 12);

  f16x4 pA[3], pB[3];
  {
    const int t0 = fwd ? 0 : (T_ - 1);
    const f16x4* p = (const f16x4*)(gbase + (size_t)t0 * 9216);
#pragma unroll
    for (int j = 0; j < 3; ++j) pA[j] = p[j];
  }
  if (nsteps > 1) {
    const int t1 = fwd ? 1 : (T_ - 2);
    const f16x4* p = (const f16x4*)(gbase + (size_t)t1 * 9216);
#pragma unroll
    for (int j = 0; j < 3; ++j) pB[j] = p[j];
  }
  __syncthreads();

  // one GRU step: consumes pc (this step's gx), then reloads pc 2 steps ahead
  auto body = [&](int step, int buf, f16x4 (&pc)[3]) {
    f32x4 acc[3];
#pragma unroll
    for (int s = 0; s < 3; ++s) {
      const float bv = bh[s];
      acc[s] = (f32x4){bv, bv, bv, bv};
    }
#pragma unroll
    for (int kt = 0; kt < 6; ++kt) {
      const f16x8 af = *(const f16x8*)(&hl[buf][l16][kt * 32 + lq * 8]);
#pragma unroll
      for (int s = 0; s < 3; ++s)
        acc[s] = __builtin_amdgcn_mfma_f32_16x16x32_f16(af, wf[s][kt], acc[s], 0, 0, 0);
    }
    // snapshot current gx values, then issue reload 2 steps ahead (WAR handled by SSA)
    const f16x4 g0 = pc[0], g1 = pc[1], g2 = pc[2];
    if (step + 2 < nsteps) {
      const int tp = fwd ? (step + 2) : (T_ - 3 - step);
      const f16x4* p = (const f16x4*)(gbase + (size_t)tp * 9216);
#pragma unroll
      for (int j = 0; j < 3; ++j) pc[j] = p[j];
    }
    const int t = fwd ? step : (T_ - 1 - step);
    const bool wr = (!last) || (t == T_ - 1);
#pragma unroll
    for (int i = 0; i < 4; ++i) {
      const float r = sigm_fast((float)g0[i] + acc[0][i]);
      const float z = sigm_fast((float)g1[i] + acc[1][i]);
      const float n = tanh_fast((float)g2[i] + r * acc[2][i]);
      const float h = n + z * (hreg[i] - n);
      hreg[i] = h;
      hl[buf ^ 1][(lq << 2) + i][w * 16 + l16] = (f16)h;
      if (wr)
        out[((size_t)t * B_ + b0 + (lq << 2) + i) * 384 + d * H_ + w * 16 + l16] = (f16)h;
    }
    // drain LDS only; prefetch loads + global stores stay in flight across barrier
    asm volatile("s_waitcnt lgkmcnt(0)" ::: "memory");
    __builtin_amdgcn_sched_barrier(0);
    __builtin_amdgcn_s_barrier();
    __builtin_amdgcn_sched_barrier(0);
  };

  if (nsteps == 1) {
    body(0, 0, pA);
  } else {
    for (int step = 0; step < T_; step += 2) {
      body(step, 0, pA);
      body(step + 1, 1, pB);
    }
  }
}

// ---------------- FC head ----------------
__global__ void fc_kernel(const f16* __restrict__ h2, const float* __restrict__ w1,
                          const float* __restrict__ b1, const float* __restrict__ w2,
                          const float* __restrict__ b2, float* __restrict__ y) {
  const int b = blockIdx.x;
  const int i = threadIdx.x;  // 128 threads = fc1 units
  __shared__ float hs[384];
  __shared__ float us[128];
  const f16* hp = h2 + ((size_t)(T_ - 1) * B_ + b) * 384;
  for (int k = i; k < 384; k += 128) hs[k] = (float)hp[k];
  __syncthreads();
  float a = b1[i];
  for (int k = 0; k < 384; ++k) a = fmaf(w1[i * 384 + k], hs[k], a);
  us[i] = fmaxf(a, 0.f) * w2[i];
  __syncthreads();
  if (i == 0) {
    float s = b2[0];
    for (int k = 0; k < 128; ++k) s += us[k];
    y[b] = s;
  }
}

extern "C" void kernel_launch(void* const* d_in, const int* in_sizes, int n_in,
                              void* d_out, int out_size, void* d_ws, size_t ws_size,
                              hipStream_t stream) {
  const int* x = (const int*)d_in[0];
  const float* emb = (const float*)d_in[1];
  const float* wih[3] = {(const float*)d_in[2], (const float*)d_in[6], (const float*)d_in[10]};
  const float* whh[3] = {(const float*)d_in[3], (const float*)d_in[7], (const float*)d_in[11]};
  const float* bih[3] = {(const float*)d_in[4], (const float*)d_in[8], (const float*)d_in[12]};
  const float* bhh[3] = {(const float*)d_in[5], (const float*)d_in[9], (const float*)d_in[13]};
  const float* fc1w = (const float*)d_in[14];
  const float* fc1b = (const float*)d_in[15];
  const float* fc2w = (const float*)d_in[16];
  const float* fc2b = (const float*)d_in[17];
  float* y = (float*)d_out;

  char* ws = (char*)d_ws;
  f16* gxb = (f16*)(ws);             // 150,994,944 B
  f16* hbuf = (f16*)(ws + OFF_H);    // 50,331,648 B (single h buffer for all layers)
  f16* in0 = hbuf;                   // embedding output aliases hbuf start (dead after gemm0)
  f16* wihf = (f16*)(ws + OFF_WIH);
  f16* whhf = (f16*)(ws + OFF_WHH);

  wconv_kernel<<<1024, 256, 0, stream>>>(wih[0], whh[0], wih[1], whh[1], wih[2], whh[2], wihf, whhf);
  embed_kernel<<<16384, 256, 0, stream>>>(x, emb, in0);

  // layer 0
  gx_gemm<128><<<dim3(512, 9), 256, 0, stream>>>(in0, wihf, bih[0], gxb);
  gru_scan<<<16, 768, 0, stream>>>(gxb, whhf, bhh[0], hbuf, 0);
  // layer 1
  gx_gemm<384><<<dim3(512, 9), 256, 0, stream>>>(hbuf, wihf + 147456, bih[1], gxb);
  gru_scan<<<16, 768, 0, stream>>>(gxb, whhf + 221184, bhh[1], hbuf, 0);
  // layer 2 (bwd dir needs only 1 step; fwd writes only t=511)
  gx_gemm<384><<<dim3(512, 9), 256, 0, stream>>>(hbuf, wihf + 147456 + 442368, bih[2], gxb);
  gru_scan<<<16, 768, 0, stream>>>(gxb, whhf + 2 * 221184, bhh[2], hbuf, 1);

  fc_kernel<<<128, 128, 0, stream>>>(hbuf, fc1w, fc1b, fc2w, fc2b, y);
}

// Round 5
// 1968.347 us; speedup vs baseline: 2.3453x; 1.0601x over previous
//
#include <hip/hip_runtime.h>

typedef _Float16 f16;
typedef _Float16 f16x8 __attribute__((ext_vector_type(8)));
typedef _Float16 f16x4 __attribute__((ext_vector_type(4)));
typedef float f32x4 __attribute__((ext_vector_type(4)));

#define B_ 128
#define T_ 512
#define H_ 192
#define G3 576
#define NX 1152

// ---- workspace layout (bytes). Total 204,718,080 < 256 MiB. ----
// [0, 150994944)          gxb : gx pre-acts, f16 [d][bblk][t][w12][lq][l16][s*4+i]
// [150994944, 201326592)  hbuf: layer h output, f16 [t][b][384]
//                               (in0 f16 [t][b][128] aliases its first 16.8MB)
// [201326592, 203390976)  wihf: f16 w_ih (L0 147456, L1 442368, L2 442368)
// [203390976, 204718080)  whhf: f16 w_hh (3 x 221184)
#define OFF_H   150994944u
#define OFF_WIH 201326592u
#define OFF_WHH 203390976u

__device__ __forceinline__ void gload_lds16(const void* g, void* l) {
  __builtin_amdgcn_global_load_lds(
      (const __attribute__((address_space(1))) unsigned int*)g,
      (__attribute__((address_space(3))) unsigned int*)l, 16, 0, 0);
}

// sigmoid/tanh with exactly 2 hardware trans ops each (v_exp_f32 + v_rcp_f32)
#define LOG2E 1.44269504088896f
__device__ __forceinline__ float sigm_fast(float x) {
  return __builtin_amdgcn_rcpf(1.f + __builtin_amdgcn_exp2f(x * -LOG2E));
}
__device__ __forceinline__ float tanh_fast(float x) {
  return fmaf(-2.f, __builtin_amdgcn_rcpf(1.f + __builtin_amdgcn_exp2f(x * (2.f * LOG2E))), 1.f);
}

// ---------------- weight f32 -> f16 conversion ----------------
__global__ void wconv_kernel(const float* __restrict__ s0, const float* __restrict__ h0,
                             const float* __restrict__ s1, const float* __restrict__ h1,
                             const float* __restrict__ s2, const float* __restrict__ h2,
                             f16* __restrict__ wih, f16* __restrict__ whh) {
  const int stride = gridDim.x * blockDim.x;
  for (int i = blockIdx.x * blockDim.x + threadIdx.x; i < 1695744; i += stride) {
    if (i < 1032192) {
      f16 v;
      if (i < 147456) v = (f16)s0[i];
      else if (i < 589824) v = (f16)s1[i - 147456];
      else v = (f16)s2[i - 589824];
      wih[i] = v;
    } else {
      int j = i - 1032192;
      f16 v;
      if (j < 221184) v = (f16)h0[j];
      else if (j < 442368) v = (f16)h1[j - 221184];
      else v = (f16)h2[j - 442368];
      whh[j] = v;
    }
  }
}

// ---------------- embedding gather -> f16, out layout [t][b][128] ----------------
__global__ void embed_kernel(const int* __restrict__ x, const float* __restrict__ emb,
                             f16* __restrict__ o) {
  const int row = (blockIdx.x << 2) + (threadIdx.x >> 6);  // b*512+t
  const int lane = threadIdx.x & 63;
  const int b = row >> 9, t = row & 511;
  const int idx = x[row];
  const float2 v = *(const float2*)(emb + ((size_t)idx << 7) + (lane << 1));
  union { f16 h[2]; unsigned u; } p;
  p.h[0] = (f16)v.x;
  p.h[1] = (f16)v.y;
  *(unsigned*)(o + ((size_t)((t << 7) + b) << 7) + (lane << 1)) = p.u;
}

// ---------------- gx GEMM: gx = X @ w_ih^T + b_ih (f16 MFMA) ----------------
template <int DIN>
__global__ __launch_bounds__(256) void gx_gemm(const f16* __restrict__ A,
                                               const f16* __restrict__ W,
                                               const float* __restrict__ bih,
                                               f16* __restrict__ gxo) {
  const int t = blockIdx.x;
  const int nt0 = blockIdx.y << 7;
  const int tid = threadIdx.x;
  const int lane = tid & 63;
  const int w = tid >> 6;
  const int l16 = lane & 15;
  const int lq = lane >> 4;
  const int wm = (w >> 1) << 6;
  const int wn = (w & 1) << 6;

  __shared__ __align__(16) f16 Al[128 * 128];
  __shared__ __align__(16) f16 Bl[128 * 128];

  f32x4 acc[4][4] = {};

  const int srow = tid >> 4;
  const int sc = tid & 15;

  for (int kk = 0; kk < DIN; kk += 128) {
    __syncthreads();
#pragma unroll
    for (int it = 0; it < 8; ++it) {
      const int r = (it << 4) + srow;
      const int cl = sc ^ (r & 7);
      gload_lds16(A + (size_t)(t * B_ + r) * DIN + kk + cl * 8, Al + (it << 11) + tid * 8);
      const int n = nt0 + r;
      gload_lds16(W + (size_t)n * DIN + kk + cl * 8, Bl + (it << 11) + tid * 8);
    }
    __syncthreads();
#pragma unroll
    for (int kt = 0; kt < 4; ++kt) {
      f16x8 af[4], bf[4];
#pragma unroll
      for (int mt = 0; mt < 4; ++mt) {
        const int r = wm + (mt << 4) + l16;
        const int c = ((kt << 2) + lq) ^ (r & 7);
        af[mt] = *(const f16x8*)(Al + (r << 7) + (c << 3));
      }
#pragma unroll
      for (int nt = 0; nt < 4; ++nt) {
        const int r = wn + (nt << 4) + l16;
        const int c = ((kt << 2) + lq) ^ (r & 7);
        bf[nt] = *(const f16x8*)(Bl + (r << 7) + (c << 3));
      }
#pragma unroll
      for (int mt = 0; mt < 4; ++mt)
#pragma unroll
        for (int nt = 0; nt < 4; ++nt)
          acc[mt][nt] = __builtin_amdgcn_mfma_f32_16x16x32_f16(af[mt], bf[nt], acc[mt][nt], 0, 0, 0);
    }
  }
#pragma unroll
  for (int nt = 0; nt < 4; ++nt) {
    const int ncol = nt0 + wn + (nt << 4);
    const float bias = bih[ncol + l16];
    const int ntile = ncol >> 4;
    const int d = (ntile >= 36) ? 1 : 0;
    const int g = ntile - 36 * d;
    const int s = g / 12;
    const int c12 = g % 12;
#pragma unroll
    for (int mt = 0; mt < 4; ++mt) {
      const int bblk = (wm >> 4) + mt;
      f16x4 pk;
#pragma unroll
      for (int i = 0; i < 4; ++i) pk[i] = (f16)(acc[mt][nt][i] + bias);
      const size_t off =
          (size_t)(((((d * 8 + bblk) * 512 + t) * 12 + c12) * 4 + lq) * 16 + l16) * 12 + s * 4;
      *(f16x4*)(gxo + off) = pk;
    }
  }
}

// ---------------- recurrent scan ----------------
// 16 blocks x 768 threads (12 waves, 3/SIMD). Wave w owns gate cols [16w,16w+16)
// for r,z,n. w_hh resident in regs/AGPRs. XOR-swizzled LDS h-tile (2-way banks,
// 16B-aligned b128 reads). All LDS addrs + global ptrs strength-reduced; b_hh
// folded into first MFMA C-input. No memory clobber in the barrier sequence.
__global__ __launch_bounds__(768, 3) void gru_scan(const f16* __restrict__ gx,
                                                   const f16* __restrict__ whh,
                                                   const float* __restrict__ bhh,
                                                   f16* __restrict__ out,
                                                   int last) {
  const int bx = blockIdx.x;
  const int d = bx & 1;
  const int bblk = bx >> 1;
  const int b0 = bblk << 4;
  const int tid = threadIdx.x;
  const int lane = tid & 63;
  const int w = tid >> 6;    // 0..11
  const int l16 = lane & 15;
  const int lq = lane >> 4;

  // h tile, XOR-swizzled: elem (row,col) at byte row*384 + ((col*2) ^ ((row&7)<<4))
  __shared__ __align__(16) f16 hl[2 * 16 * 192];   // 12,288 B
  for (int i = tid; i < 2 * 16 * 192; i += 768) hl[i] = (f16)0.f;
  char* cb = (char*)hl;

  // precomputed LDS addresses (buf1 = +6144 via offset imm)
  int ra[6];
#pragma unroll
  for (int kt = 0; kt < 6; ++kt)
    ra[kt] = l16 * 384 + ((kt * 64 + lq * 16) ^ ((l16 & 7) << 4));
  int wa[4];
#pragma unroll
  for (int i = 0; i < 4; ++i) {
    const int row = lq * 4 + i;
    wa[i] = row * 384 + (((w * 16 + l16) * 2) ^ ((row & 7) << 4));
  }

  const f16* whd = whh + (size_t)d * (G3 * H_);
  f16x8 wf[3][6];
#pragma unroll
  for (int s = 0; s < 3; ++s) {
    const int nrow = s * 192 + w * 16 + l16;
#pragma unroll
    for (int kt = 0; kt < 6; ++kt)
      wf[s][kt] = *(const f16x8*)(whd + (size_t)nrow * H_ + kt * 32 + lq * 8);
  }
  f32x4 bh4[3];
#pragma unroll
  for (int s = 0; s < 3; ++s) {
    const float bv = bhh[d * G3 + s * 192 + w * 16 + l16];
    bh4[s] = (f32x4){bv, bv, bv, bv};
  }

  float hreg[4];
#pragma unroll
  for (int i = 0; i < 4; ++i) hreg[i] = 0.f;

  const int nsteps = (last && d == 1) ? 1 : T_;
  const bool fwd = (d == 0);
  const long gstep = fwd ? 9216 : -9216;          // f16 elems per step
  const long ostep = fwd ? (long)B_ * 384 : -(long)B_ * 384;

  const f16* gbase = gx + (size_t)(d * 8 + bblk) * 4718592 +
                     (size_t)(((w * 4 + lq) * 16 + l16) * 12);
  const int t0 = fwd ? 0 : (T_ - 1);

  // prefetch first two steps' gx
  f16x4 pA[3], pB[3];
  {
    const f16x4* p = (const f16x4*)(gbase + (size_t)t0 * 9216);
#pragma unroll
    for (int j = 0; j < 3; ++j) pA[j] = p[j];
  }
  if (nsteps > 1) {
    const f16x4* p = (const f16x4*)(gbase + (size_t)t0 * 9216 + gstep);
#pragma unroll
    for (int j = 0; j < 3; ++j) pB[j] = p[j];
  }
  const f16* gptr = gbase + (size_t)t0 * 9216 + 2 * gstep;  // 2 steps ahead
  f16* outp = out + ((size_t)t0 * B_ + b0 + (lq << 2)) * 384 + d * H_ + w * 16 + l16;

  __syncthreads();

  // one GRU step: consumes pc (this step's gx), reloads pc 2 steps ahead
  auto body = [&](int step, int buf, f16x4 (&pc)[3]) {
    const int bo = buf ? 6144 : 0;
    // gh = h @ w_hh^T with b_hh as C-init of the first MFMA
    f32x4 acc[3];
    {
      const f16x8 af0 = *(const f16x8*)(cb + ra[0] + bo);
#pragma unroll
      for (int s = 0; s < 3; ++s)
        acc[s] = __builtin_amdgcn_mfma_f32_16x16x32_f16(af0, wf[s][0], bh4[s], 0, 0, 0);
    }
#pragma unroll
    for (int kt = 1; kt < 6; ++kt) {
      const f16x8 af = *(const f16x8*)(cb + ra[kt] + bo);
#pragma unroll
      for (int s = 0; s < 3; ++s)
        acc[s] = __builtin_amdgcn_mfma_f32_16x16x32_f16(af, wf[s][kt], acc[s], 0, 0, 0);
    }
    // snapshot current gx, issue reload 2 steps ahead
    const f16x4 g0 = pc[0], g1 = pc[1], g2 = pc[2];
    if (step + 2 < nsteps) {
      const f16x4* p = (const f16x4*)gptr;
#pragma unroll
      for (int j = 0; j < 3; ++j) pc[j] = p[j];
      gptr += gstep;
    }
    const int t = fwd ? step : (T_ - 1 - step);
    const bool wr = (!last) || (t == T_ - 1);
    const int bo2 = buf ? 0 : 6144;   // write to other buffer
#pragma unroll
    for (int i = 0; i < 4; ++i) {
      const float r = sigm_fast((float)g0[i] + acc[0][i]);
      const float z = sigm_fast((float)g1[i] + acc[1][i]);
      const float n = tanh_fast((float)g2[i] + r * acc[2][i]);
      const float h = n + z * (hreg[i] - n);
      hreg[i] = h;
      *(f16*)(cb + wa[i] + bo2) = (f16)h;
      if (wr) outp[i * 384] = (f16)h;
    }
    outp += ostep;
    // HK barrier pattern: order LDS, keep global loads/stores in flight
    __builtin_amdgcn_sched_barrier(0);
    asm volatile("s_waitcnt lgkmcnt(0)");
    __builtin_amdgcn_s_barrier();
    __builtin_amdgcn_sched_barrier(0);
  };

  if (nsteps == 1) {
    body(0, 0, pA);
  } else {
    for (int step = 0; step < T_; step += 2) {
      body(step, 0, pA);
      body(step + 1, 1, pB);
    }
  }
}

// ---------------- FC head ----------------
__global__ void fc_kernel(const f16* __restrict__ h2, const float* __restrict__ w1,
                          const float* __restrict__ b1, const float* __restrict__ w2,
                          const float* __restrict__ b2, float* __restrict__ y) {
  const int b = blockIdx.x;
  const int i = threadIdx.x;
  __shared__ float hs[384];
  __shared__ float us[128];
  const f16* hp = h2 + ((size_t)(T_ - 1) * B_ + b) * 384;
  for (int k = i; k < 384; k += 128) hs[k] = (float)hp[k];
  __syncthreads();
  float a = b1[i];
  for (int k = 0; k < 384; ++k) a = fmaf(w1[i * 384 + k], hs[k], a);
  us[i] = fmaxf(a, 0.f) * w2[i];
  __syncthreads();
  if (i == 0) {
    float s = b2[0];
    for (int k = 0; k < 128; ++k) s += us[k];
    y[b] = s;
  }
}

extern "C" void kernel_launch(void* const* d_in, const int* in_sizes, int n_in,
                              void* d_out, int out_size, void* d_ws, size_t ws_size,
                              hipStream_t stream) {
  const int* x = (const int*)d_in[0];
  const float* emb = (const float*)d_in[1];
  const float* wih[3] = {(const float*)d_in[2], (const float*)d_in[6], (const float*)d_in[10]};
  const float* whh[3] = {(const float*)d_in[3], (const float*)d_in[7], (const float*)d_in[11]};
  const float* bih[3] = {(const float*)d_in[4], (const float*)d_in[8], (const float*)d_in[12]};
  const float* bhh[3] = {(const float*)d_in[5], (const float*)d_in[9], (const float*)d_in[13]};
  const float* fc1w = (const float*)d_in[14];
  const float* fc1b = (const float*)d_in[15];
  const float* fc2w = (const float*)d_in[16];
  const float* fc2b = (const float*)d_in[17];
  float* y = (float*)d_out;

  char* ws = (char*)d_ws;
  f16* gxb = (f16*)(ws);
  f16* hbuf = (f16*)(ws + OFF_H);
  f16* in0 = hbuf;
  f16* wihf = (f16*)(ws + OFF_WIH);
  f16* whhf = (f16*)(ws + OFF_WHH);

  wconv_kernel<<<1024, 256, 0, stream>>>(wih[0], whh[0], wih[1], whh[1], wih[2], whh[2], wihf, whhf);
  embed_kernel<<<16384, 256, 0, stream>>>(x, emb, in0);

  gx_gemm<128><<<dim3(512, 9), 256, 0, stream>>>(in0, wihf, bih[0], gxb);
  gru_scan<<<16, 768, 0, stream>>>(gxb, whhf, bhh[0], hbuf, 0);
  gx_gemm<384><<<dim3(512, 9), 256, 0, stream>>>(hbuf, wihf + 147456, bih[1], gxb);
  gru_scan<<<16, 768, 0, stream>>>(gxb, whhf + 221184, bhh[1], hbuf, 0);
  gx_gemm<384><<<dim3(512, 9), 256, 0, stream>>>(hbuf, wihf + 147456 + 442368, bih[2], gxb);
  gru_scan<<<16, 768, 0, stream>>>(gxb, whhf + 2 * 221184, bhh[2], hbuf, 1);

  fc_kernel<<<128, 128, 0, stream>>>(hbuf, fc1w, fc1b, fc2w, fc2b, y);
}